// Round 1
// baseline (1294.485 us; speedup 1.0000x reference)
//
#include <hip/hip_runtime.h>

typedef __bf16 bf16_t;
typedef __bf16 bf16x8 __attribute__((ext_vector_type(8)));
typedef float f32x4 __attribute__((ext_vector_type(4)));

// ---------------------------------------------------------------------------
// GEMM: C[M][N] = A[M][K] @ Bt[N][K]^T + bias[N], optional relu,
// writes fp32 and/or bf16 outputs. 128x128 tile, BK=32, 4 waves, 4x4 MFMA
// 16x16x32 per wave. A and Bt are bf16 row-major with K contiguous.
// ---------------------------------------------------------------------------
#define BM 128
#define BN 128
#define BK 32
#define LDK 40  // padded LDS row stride (elements); 80 B = multiple of 16 B

__global__ __launch_bounds__(256, 2)
void gemm_bf16(const bf16_t* __restrict__ A, const bf16_t* __restrict__ Bt,
               const float* __restrict__ bias, float* __restrict__ Cf,
               bf16_t* __restrict__ Cbf, int M, int N, int K, int relu)
{
    __shared__ bf16_t As[BM * LDK];
    __shared__ bf16_t Bs[BN * LDK];

    const int tid  = threadIdx.x;
    const int m0   = blockIdx.y * BM;
    const int n0   = blockIdx.x * BN;
    const int wave = tid >> 6;
    const int lane = tid & 63;
    const int wm   = (wave & 1) * 64;   // wave row offset in block tile
    const int wn   = (wave >> 1) * 64;  // wave col offset
    const int lr   = lane & 15;         // A row / B col within 16-tile
    const int lq   = lane >> 4;         // quad 0..3 -> k-offset lq*8

    f32x4 acc[4][4];
#pragma unroll
    for (int i = 0; i < 4; i++)
#pragma unroll
        for (int j = 0; j < 4; j++) acc[i][j] = (f32x4){0.f, 0.f, 0.f, 0.f};

    // staging: 512 chunks of 8 bf16 per tile; 256 threads x 2 chunks
    const int c0 = tid, c1 = tid + 256;
    const int ar0 = c0 >> 2, ak0 = (c0 & 3) * 8;
    const int ar1 = c1 >> 2, ak1 = (c1 & 3) * 8;

    const bf16_t* Aptr = A + (long)m0 * K;
    const bf16_t* Bptr = Bt + (long)n0 * K;

    for (int k0 = 0; k0 < K; k0 += BK) {
        uint4 av0 = *(const uint4*)(Aptr + (long)ar0 * K + k0 + ak0);
        uint4 av1 = *(const uint4*)(Aptr + (long)ar1 * K + k0 + ak1);
        uint4 bv0 = *(const uint4*)(Bptr + (long)ar0 * K + k0 + ak0);
        uint4 bv1 = *(const uint4*)(Bptr + (long)ar1 * K + k0 + ak1);
        __syncthreads();  // previous iteration's LDS reads complete
        *(uint4*)&As[ar0 * LDK + ak0] = av0;
        *(uint4*)&As[ar1 * LDK + ak1] = av1;
        *(uint4*)&Bs[ar0 * LDK + ak0] = bv0;
        *(uint4*)&Bs[ar1 * LDK + ak1] = bv1;
        __syncthreads();

        bf16x8 af[4], bfr[4];
#pragma unroll
        for (int i = 0; i < 4; i++) {
            af[i]  = *(bf16x8*)&As[(wm + i * 16 + lr) * LDK + lq * 8];
            bfr[i] = *(bf16x8*)&Bs[(wn + i * 16 + lr) * LDK + lq * 8];
        }
#pragma unroll
        for (int i = 0; i < 4; i++)
#pragma unroll
            for (int j = 0; j < 4; j++)
                acc[i][j] = __builtin_amdgcn_mfma_f32_16x16x32_bf16(
                    af[i], bfr[j], acc[i][j], 0, 0, 0);
    }

    // epilogue: D row = m0+wm+i*16+lq*4+r, col = n0+wn+j*16+lr
#pragma unroll
    for (int i = 0; i < 4; i++) {
#pragma unroll
        for (int j = 0; j < 4; j++) {
            const int col = n0 + wn + j * 16 + lr;
            const float bval = bias[col];
#pragma unroll
            for (int r = 0; r < 4; r++) {
                const int row = m0 + wm + i * 16 + lq * 4 + r;
                float v = acc[i][j][r] + bval;
                if (relu) v = fmaxf(v, 0.f);
                const long idx = (long)row * N + col;
                if (Cf)  Cf[idx] = v;
                if (Cbf) Cbf[idx] = (bf16_t)v;
            }
        }
    }
}

// ---------------------------------------------------------------------------
// fp32 -> bf16 elementwise cast (8 elems/thread), n % 8 == 0
// ---------------------------------------------------------------------------
__global__ void cast_bf16(const float* __restrict__ in, bf16_t* __restrict__ out,
                          long n)
{
    long i = ((long)blockIdx.x * blockDim.x + threadIdx.x) * 8;
    if (i + 8 > n) return;
    float4 f0 = *(const float4*)(in + i);
    float4 f1 = *(const float4*)(in + i + 4);
    union { bf16_t h[8]; uint4 u; } cv;
    cv.h[0] = (bf16_t)f0.x; cv.h[1] = (bf16_t)f0.y;
    cv.h[2] = (bf16_t)f0.z; cv.h[3] = (bf16_t)f0.w;
    cv.h[4] = (bf16_t)f1.x; cv.h[5] = (bf16_t)f1.y;
    cv.h[6] = (bf16_t)f1.z; cv.h[7] = (bf16_t)f1.w;
    *(uint4*)(out + i) = cv.u;
}

// ---------------------------------------------------------------------------
// transpose + cast: in fp32 [R][C] row-major  ->  out bf16 [C][R] row-major
// R, C multiples of 32. block (32,8), 32x32 tiles, z = batch.
// ---------------------------------------------------------------------------
__global__ void transpose_cast(const float* __restrict__ in, bf16_t* __restrict__ out,
                               int R, int C, long inStrideZ, long outStrideZ)
{
    __shared__ float t[32][33];
    const float* inz = in + inStrideZ * blockIdx.z;
    bf16_t* outz = out + outStrideZ * blockIdx.z;
    const int c0 = blockIdx.x * 32;
    const int r0 = blockIdx.y * 32;
    const int tx = threadIdx.x, ty = threadIdx.y;
#pragma unroll
    for (int dy = 0; dy < 32; dy += 8)
        t[ty + dy][tx] = inz[(long)(r0 + ty + dy) * C + c0 + tx];
    __syncthreads();
#pragma unroll
    for (int dy = 0; dy < 32; dy += 8)
        outz[(long)(c0 + ty + dy) * R + r0 + tx] = (bf16_t)t[tx][ty + dy];
}

// ---------------------------------------------------------------------------
// X = LayerNorm(X + O)  (population var, no eps, no affine), writes fp32 + bf16
// one block per row, D = 768, 256 threads x 3 elems
// ---------------------------------------------------------------------------
__global__ __launch_bounds__(256)
void ln_residual(float* __restrict__ X, const float* __restrict__ O,
                 bf16_t* __restrict__ Xbf)
{
    __shared__ float red[8];
    const long base = (long)blockIdx.x * 768;
    const int tid = threadIdx.x;
    float s[3];
#pragma unroll
    for (int j = 0; j < 3; j++) {
        const int idx = tid + j * 256;
        s[j] = X[base + idx] + O[base + idx];
    }
    float sum = s[0] + s[1] + s[2];
    for (int o = 32; o > 0; o >>= 1) sum += __shfl_down(sum, o, 64);
    if ((tid & 63) == 0) red[tid >> 6] = sum;
    __syncthreads();
    const float mu = (red[0] + red[1] + red[2] + red[3]) * (1.0f / 768.0f);
    float d0 = s[0] - mu, d1 = s[1] - mu, d2 = s[2] - mu;
    float sq = d0 * d0 + d1 * d1 + d2 * d2;
    for (int o = 32; o > 0; o >>= 1) sq += __shfl_down(sq, o, 64);
    if ((tid & 63) == 0) red[4 + (tid >> 6)] = sq;
    __syncthreads();
    const float var = (red[4] + red[5] + red[6] + red[7]) * (1.0f / 768.0f);
    const float rstd = 1.0f / sqrtf(var);
#pragma unroll
    for (int j = 0; j < 3; j++) {
        const int idx = tid + j * 256;
        const float v = (s[j] - mu) * rstd;
        X[base + idx] = v;
        Xbf[base + idx] = (bf16_t)v;
    }
}

// ---------------------------------------------------------------------------
// in-place row softmax over 8192 cols; one block per row, 32 elems/thread
// ---------------------------------------------------------------------------
__global__ __launch_bounds__(256)
void softmax_inplace(float* __restrict__ P)
{
    __shared__ float red[8];
    const long base = (long)blockIdx.x * 8192;
    const int tid = threadIdx.x;
    float v[32];
    float mx = -1e30f;
#pragma unroll
    for (int j = 0; j < 32; j++) {
        v[j] = P[base + tid + j * 256];
        mx = fmaxf(mx, v[j]);
    }
    for (int o = 32; o > 0; o >>= 1) mx = fmaxf(mx, __shfl_down(mx, o, 64));
    if ((tid & 63) == 0) red[tid >> 6] = mx;
    __syncthreads();
    mx = fmaxf(fmaxf(red[0], red[1]), fmaxf(red[2], red[3]));
    float sum = 0.f;
#pragma unroll
    for (int j = 0; j < 32; j++) {
        v[j] = __expf(v[j] - mx);
        sum += v[j];
    }
    for (int o = 32; o > 0; o >>= 1) sum += __shfl_down(sum, o, 64);
    if ((tid & 63) == 0) red[4 + (tid >> 6)] = sum;
    __syncthreads();
    const float inv = 1.0f / (red[4] + red[5] + red[6] + red[7]);
#pragma unroll
    for (int j = 0; j < 32; j++) P[base + tid + j * 256] = v[j] * inv;
}

// ---------------------------------------------------------------------------
extern "C" void kernel_launch(void* const* d_in, const int* in_sizes, int n_in,
                              void* d_out, int out_size, void* d_ws, size_t ws_size,
                              hipStream_t stream)
{
    (void)in_sizes; (void)n_in; (void)out_size; (void)ws_size;
    const float* X0   = (const float*)d_in[0];
    const float* embw = (const float*)d_in[1];
    const float* embb = (const float*)d_in[2];
    // d_in[3..6] = Wq,bq,Wk,bk : unused (softmax rows sum to 1 => head_out == V)
    const float* Wv   = (const float*)d_in[7];
    const float* bv   = (const float*)d_in[8];
    const float* Wo   = (const float*)d_in[9];
    const float* bo   = (const float*)d_in[10];
    const float* W1   = (const float*)d_in[11];
    const float* b1   = (const float*)d_in[12];
    const float* W2   = (const float*)d_in[13];
    const float* b2   = (const float*)d_in[14];
    const float* Wout = (const float*)d_in[15];
    const float* bout = (const float*)d_in[16];
    float* out = (float*)d_out;

    // workspace layout (~151 MB). X0bf region is reused after the embed GEMM
    // for tmpF / Vcat / Hid (lifetimes are disjoint).
    char* base = (char*)d_ws;
    bf16_t* X0bf = (bf16_t*)base;                    // 67,108,864 B
    float*  tmpF = (float*)base;                     // alias, 12,582,912 B
    bf16_t* Vcat = (bf16_t*)(base + 12582912);       // 6,291,456 B
    bf16_t* Hid  = (bf16_t*)(base + 18874368);       // 25,165,824 B (ends 44 MB)
    char* p = base + 67108864;
    bf16_t* embT  = (bf16_t*)p; p += 12582912;       // [768][8192]
    bf16_t* WoutT = (bf16_t*)p; p += 12582912;       // [8192][768]
    bf16_t* WvT   = (bf16_t*)p; p += 4718592;        // 4 x [768][768]
    bf16_t* WoT   = (bf16_t*)p; p += 4718592;        // 4 x [768][768]
    bf16_t* W1T   = (bf16_t*)p; p += 18874368;       // 4 x [3072][768]
    bf16_t* W2T   = (bf16_t*)p; p += 18874368;       // 4 x [768][3072]
    float*  Xf    = (float*)p;  p += 12582912;       // residual stream fp32
    bf16_t* Xbf   = (bf16_t*)p; p += 6291456;        // bf16 copy of Xf

    const dim3 tb(32, 8);

    // input + weight conversion (weights transposed to [N][K] bf16)
    cast_bf16<<<16384, 256, 0, stream>>>(X0, X0bf, (long)33554432);
    transpose_cast<<<dim3(24, 256, 1), tb, 0, stream>>>(embw, embT, 8192, 768, 0, 0);
    transpose_cast<<<dim3(256, 24, 1), tb, 0, stream>>>(Wout, WoutT, 768, 8192, 0, 0);
    // Wv: z = i*12+h, each head is a 768x64 slab -> rows h*64..h*64+63 of WvT_i
    transpose_cast<<<dim3(2, 24, 48), tb, 0, stream>>>(Wv, WvT, 768, 64, 49152, 49152);
    transpose_cast<<<dim3(24, 24, 4), tb, 0, stream>>>(Wo, WoT, 768, 768, 589824, 589824);
    transpose_cast<<<dim3(96, 24, 4), tb, 0, stream>>>(W1, W1T, 768, 3072, 2359296, 2359296);
    transpose_cast<<<dim3(24, 96, 4), tb, 0, stream>>>(W2, W2T, 3072, 768, 2359296, 2359296);

    // embedding: X = X0 @ emb_w + emb_b   [4096, 768], K = 8192
    gemm_bf16<<<dim3(6, 32), 256, 0, stream>>>(X0bf, embT, embb, Xf, Xbf,
                                               4096, 768, 8192, 0);

    for (int i = 0; i < 4; i++) {
        // Vcat = X @ Wv_flat + bv   (attention collapses to identity on V)
        gemm_bf16<<<dim3(6, 32), 256, 0, stream>>>(
            Xbf, WvT + (size_t)i * 589824, bv + i * 768, nullptr, Vcat,
            4096, 768, 768, 0);
        // O = Vcat @ Wo + bo
        gemm_bf16<<<dim3(6, 32), 256, 0, stream>>>(
            Vcat, WoT + (size_t)i * 589824, bo + i * 768, tmpF, nullptr,
            4096, 768, 768, 0);
        ln_residual<<<4096, 256, 0, stream>>>(Xf, tmpF, Xbf);
        // Hid = relu(X @ W1 + b1)
        gemm_bf16<<<dim3(24, 32), 256, 0, stream>>>(
            Xbf, W1T + (size_t)i * 2359296, b1 + i * 3072, nullptr, Hid,
            4096, 3072, 768, 1);
        // F = Hid @ W2 + b2
        gemm_bf16<<<dim3(6, 32), 256, 0, stream>>>(
            Hid, W2T + (size_t)i * 2359296, b2 + i * 768, tmpF, nullptr,
            4096, 768, 3072, 0);
        ln_residual<<<4096, 256, 0, stream>>>(Xf, tmpF, Xbf);
    }

    // logits into d_out, then in-place softmax
    gemm_bf16<<<dim3(64, 32), 256, 0, stream>>>(Xbf, WoutT, bout, out, nullptr,
                                                4096, 8192, 768, 0);
    softmax_inplace<<<4096, 256, 0, stream>>>(out);
}